// Round 7
// baseline (214.043 us; speedup 1.0000x reference)
//
#include <hip/hip_runtime.h>
#include <hip/hip_bf16.h>
#include <math.h>

// AttentionPooling: B=128, S=2048, D=128, NQ=18 (fp32 in/out)
// R6 (resubmit; R6 bench was an infra timeout): raw-barrier pipeline.
// Double-buffered subtiled x_lds; q hi/lo fragments in registers (per-wave);
// barriers are asm lgkmcnt(0) + s_barrier + sched_barrier(0) -- NO vmcnt
// drain, so the next tile's 32KB global fetch stays in flight across the
// whole current tile (QK+softmax+PV). The only vmcnt wait is the compiler's
// counted wait when stage_store consumes pf.

#define BB 128
#define SS 2048
#define DD 128
#define NQ 18
#define NCHUNK 8
#define CHUNK 256
#define TILE 64
#define NTILES 4
#define SCALE 0.08838834764831845f   // 1/sqrt(128)
#define REC_F (NQ * 2 + NQ * DD)
#define ACC_OFF (NQ * 2)

typedef __attribute__((ext_vector_type(4))) float f32x4;
typedef __attribute__((ext_vector_type(8))) short short8v;
typedef __attribute__((ext_vector_type(2))) int i32x2;

#define MFMA16(a, b, c) __builtin_amdgcn_mfma_f32_16x16x32_bf16(a, b, c, 0, 0, 0)

// producer->consumer LDS sync WITHOUT vmcnt drain (HK pattern, guide §5)
#define BLOCK_SYNC() do {                                      \
    asm volatile("s_waitcnt lgkmcnt(0)" ::: "memory");         \
    __builtin_amdgcn_s_barrier();                              \
    __builtin_amdgcn_sched_barrier(0);                         \
} while (0)

__device__ __forceinline__ short bfc(float f) {
    __hip_bfloat16 h = __float2bfloat16(f);
    return *reinterpret_cast<short*>(&h);
}
__device__ __forceinline__ float bf2f(short s) {
    return __uint_as_float(((unsigned)(unsigned short)s) << 16);
}

__global__ __launch_bounds__(256, 3) void ap_partial(
    const float* __restrict__ x, const float* __restrict__ q_emb,
    const int* __restrict__ questions, const int* __restrict__ mask,
    float* __restrict__ ws)
{
    // x tile: 32 blocks (row-blk 0..3 x d-blk 0..7) of 16x16 bf16; block
    // inner (halfwords) ((r>>2)&3)*64 + (r&3)*16 + (d&15); stride 264 hw.
    __shared__ __align__(16) short x_lds[2][32 * 264];  // 2 x 16.9 KB
    __shared__ __align__(16) short p_lds[32 * 80];      // [j][row+pad] bf16
    __shared__ float lw_lds[4][32];

    const int tid = threadIdx.x;
    const int b = blockIdx.x >> 3, c = blockIdx.x & 7;
    const size_t rowbase = (size_t)b * SS + (size_t)c * CHUNK;
    const int w = tid >> 6, lane = tid & 63;
    const int lm = lane & 15, hg = lane >> 4;

    // ---- q fragments in registers: scaled, hi/lo split bf16 ----
    short8v qh[2][4], ql[2][4];
    #pragma unroll
    for (int nt = 0; nt < 2; ++nt) {
        const int j = nt * 16 + lm;
        const bool valid = j < NQ;
        const int qrow = valid ? questions[b * NQ + j] : 0;
        const float* qb = q_emb + (size_t)qrow * DD + 8 * hg;
        #pragma unroll
        for (int kt = 0; kt < 4; ++kt) {
            float v[8];
            if (valid) {
                const float4 a0 = *(const float4*)(qb + kt * 32);
                const float4 a1 = *(const float4*)(qb + kt * 32 + 4);
                v[0] = a0.x; v[1] = a0.y; v[2] = a0.z; v[3] = a0.w;
                v[4] = a1.x; v[5] = a1.y; v[6] = a1.z; v[7] = a1.w;
            } else {
                #pragma unroll
                for (int i = 0; i < 8; ++i) v[i] = 0.f;
            }
            #pragma unroll
            for (int i = 0; i < 8; ++i) {
                const float s = v[i] * SCALE;
                const short h = bfc(s);
                qh[nt][kt][i] = h;
                ql[nt][kt][i] = bfc(s - bf2f(h));
            }
        }
    }

    auto stage_load = [&](int t, float4 pf[8]) {
        const float* xb = x + (rowbase + (size_t)t * TILE) * DD;
        #pragma unroll
        for (int i = 0; i < 8; ++i) {
            const int quad = i * 256 + tid;
            pf[i] = *(const float4*)(xb + (size_t)(quad >> 5) * DD + (quad & 31) * 4);
        }
    };
    auto stage_store = [&](const float4 pf[8], int buf) {
        #pragma unroll
        for (int i = 0; i < 8; ++i) {
            const int quad = i * 256 + tid;
            const int r = quad >> 5, d = (quad & 31) * 4;
            const int idx = ((r >> 4) * 8 + (d >> 4)) * 264
                          + ((r >> 2) & 3) * 64 + (r & 3) * 16 + (d & 15);
            short4 h;
            h.x = bfc(pf[i].x); h.y = bfc(pf[i].y);
            h.z = bfc(pf[i].z); h.w = bfc(pf[i].w);
            *(short4*)&x_lds[buf][idx] = h;
        }
    };

    float4 pf[8];
    stage_load(0, pf);
    stage_store(pf, 0);
    BLOCK_SYNC();                                 // buf0 ready

    float lp0 = 0.f, lp1 = 0.f;
    f32x4 acc[2][2];
    #pragma unroll
    for (int mt = 0; mt < 2; ++mt)
        #pragma unroll
        for (int nt = 0; nt < 2; ++nt)
            acc[mt][nt] = (f32x4){0.f, 0.f, 0.f, 0.f};

    for (int t = 0; t < NTILES; ++t) {
        const int cur = t & 1;
        // issue next tile's global loads NOW; they stay in flight across
        // both raw barriers (no vmcnt drain) until stage_store at tile end.
        if (t + 1 < NTILES) stage_load(t + 1, pf);

        // ---- QK: scores^T for wave's 16 rows (q from registers) ----
        f32x4 sc0 = {0.f, 0.f, 0.f, 0.f}, sc1 = {0.f, 0.f, 0.f, 0.f};
        #pragma unroll
        for (int kt = 0; kt < 4; ++kt) {
            const short8v a = *(const short8v*)&x_lds[cur][
                (w * 8 + kt * 2 + (hg >> 1)) * 264
                + (lm >> 2) * 64 + (lm & 3) * 16 + (hg & 1) * 8];
            sc0 = MFMA16(a, qh[0][kt], sc0);
            sc0 = MFMA16(a, ql[0][kt], sc0);
            sc1 = MFMA16(a, qh[1][kt], sc1);
            sc1 = MFMA16(a, ql[1][kt], sc1);
        }

        // ---- mask + exp (no max subtraction), p -> p_lds, l running ----
        const int4 mk = *(const int4*)(mask + rowbase + t * TILE + w * 16 + 4 * hg);
        const int mka[4] = {mk.x, mk.y, mk.z, mk.w};
        float p0[4], p1[4];
        #pragma unroll
        for (int r = 0; r < 4; ++r) {
            p0[r] = mka[r] ? __expf(sc0[r]) : 0.f;
            p1[r] = mka[r] ? __expf(sc1[r]) : 0.f;
            lp0 += p0[r];
            lp1 += p1[r];
        }
        short4 pk0, pk1;
        pk0.x = bfc(p0[0]); pk0.y = bfc(p0[1]); pk0.z = bfc(p0[2]); pk0.w = bfc(p0[3]);
        pk1.x = bfc(p1[0]); pk1.y = bfc(p1[1]); pk1.z = bfc(p1[2]); pk1.w = bfc(p1[3]);
        *(short4*)&p_lds[lm * 80        + w * 16 + 4 * hg] = pk0;
        *(short4*)&p_lds[(16 + lm) * 80 + w * 16 + 4 * hg] = pk1;
        BLOCK_SYNC();                             // p published (loads still in flight)

        // ---- PV: out[j][d], A = p, B = x via tr-reads ----
        const unsigned x_base = (unsigned)(uintptr_t)(&x_lds[cur][0]);
        #pragma unroll
        for (int kt = 0; kt < 2; ++kt) {
            const short8v pa0 = *(const short8v*)&p_lds[lm * 80        + kt * 32 + 8 * hg];
            const short8v pa1 = *(const short8v*)&p_lds[(16 + lm) * 80 + kt * 32 + 8 * hg];
            #pragma unroll
            for (int nt = 0; nt < 2; ++nt) {
                const unsigned blk = (unsigned)((kt * 2 + (hg >> 1)) * 8 + (w * 2 + nt));
                const unsigned va = x_base + blk * 528u + (unsigned)(2 * (hg & 1)) * 128u
                                  + (unsigned)lm * 8u;
                i32x2 t0, t1;
                asm volatile("ds_read_b64_tr_b16 %0, %2\n\t"
                             "ds_read_b64_tr_b16 %1, %2 offset:128\n\t"
                             "s_waitcnt lgkmcnt(0)"
                             : "=&v"(t0), "=&v"(t1) : "v"(va) : "memory");
                __builtin_amdgcn_sched_barrier(0);
                union { i32x2 p[2]; short8v s; } u;
                u.p[0] = t0; u.p[1] = t1;
                acc[0][nt] = MFMA16(pa0, u.s, acc[0][nt]);
                acc[1][nt] = MFMA16(pa1, u.s, acc[1][nt]);
            }
        }
        // stage next tile into the other buffer (compiler inserts the counted
        // vmcnt wait on pf here -- ~2000 cycles after issue).
        if (t + 1 < NTILES) stage_store(pf, cur ^ 1);
        BLOCK_SYNC();                             // x[cur^1] ready, p_lds reusable
    }

    // ---- l reduction across hg then waves; write record ----
    lp0 += __shfl_xor(lp0, 16); lp0 += __shfl_xor(lp0, 32);
    lp1 += __shfl_xor(lp1, 16); lp1 += __shfl_xor(lp1, 32);
    if (lane < 16) { lw_lds[w][lm] = lp0; lw_lds[w][16 + lm] = lp1; }
    __syncthreads();

    float* recp = ws + (size_t)(b * NCHUNK + c) * REC_F;
    if (tid < NQ) {
        recp[tid] = 0.f;                           // m record: constant 0
        recp[NQ + tid] = lw_lds[0][tid] + lw_lds[1][tid]
                       + lw_lds[2][tid] + lw_lds[3][tid];
    }
    float* accp = recp + ACC_OFF;
    #pragma unroll
    for (int mt = 0; mt < 2; ++mt)
        #pragma unroll
        for (int nt = 0; nt < 2; ++nt)
            #pragma unroll
            for (int r = 0; r < 4; ++r) {
                const int j = mt * 16 + 4 * hg + r;
                if (j < NQ)
                    accp[j * DD + w * 32 + nt * 16 + lm] = acc[mt][nt][r];
            }
}

// one wave per (b, j): merge NCHUNK partials, normalize, write out
__global__ __launch_bounds__(256) void ap_combine(
    const float* __restrict__ ws, float* __restrict__ out)
{
    const int lane = threadIdx.x & 63;
    const int wv   = threadIdx.x >> 6;
    const int pair = blockIdx.x * 4 + wv;     // < B*NQ = 2304
    const int b = pair / NQ;
    const int j = pair % NQ;

    float mc[NCHUNK], lc[NCHUNK];
    float M = -1e30f;
    #pragma unroll
    for (int c = 0; c < NCHUNK; ++c) {
        const float* recp = ws + (size_t)(b * NCHUNK + c) * REC_F;
        mc[c] = recp[j];
        lc[c] = recp[NQ + j];
        M = fmaxf(M, mc[c]);
    }
    float L = 0.f;
    float w[NCHUNK];
    #pragma unroll
    for (int c = 0; c < NCHUNK; ++c) {
        w[c] = (lc[c] > 0.f) ? __expf(mc[c] - M) : 0.f;
        L = fmaf(lc[c], w[c], L);
    }
    const float inv = 1.0f / L;

    float o0 = 0.f, o1 = 0.f;
    #pragma unroll
    for (int c = 0; c < NCHUNK; ++c) {
        const float* accp = ws + (size_t)(b * NCHUNK + c) * REC_F + ACC_OFF + j * DD;
        o0 = fmaf(w[c], accp[lane],      o0);
        o1 = fmaf(w[c], accp[lane + 64], o1);
    }
    float* op = out + ((size_t)b * NQ + j) * DD;
    op[lane]      = o0 * inv;
    op[lane + 64] = o1 * inv;
}

extern "C" void kernel_launch(void* const* d_in, const int* in_sizes, int n_in,
                              void* d_out, int out_size, void* d_ws, size_t ws_size,
                              hipStream_t stream)
{
    const float* x         = (const float*)d_in[0];
    const float* q_emb     = (const float*)d_in[1];
    const int*   questions = (const int*)d_in[2];
    const int*   mask      = (const int*)d_in[3];
    float* out = (float*)d_out;
    float* ws  = (float*)d_ws;   // 1024 * 2340 * 4 B = 9.6 MB

    hipLaunchKernelGGL(ap_partial, dim3(BB * NCHUNK), dim3(256), 0, stream,
                       x, q_emb, questions, mask, ws);
    hipLaunchKernelGGL(ap_combine, dim3(BB * NQ / 4), dim3(256), 0, stream,
                       ws, out);
}